// Round 2
// baseline (261.553 us; speedup 1.0000x reference)
//
#include <hip/hip_runtime.h>
#include <hip/hip_bf16.h>

#define BB 64
#define SS 4096
#define EE 128   // EMB_DIM
#define DD 128   // DEC_DIM
#define FAN 256
#define TILES 2            // 64-row s-tiles per logits block
#define ROWS (TILES * 64)  // 128 s-rows per block
#define NEG_INF_F (-1e10f)

typedef __bf16 bf16x8 __attribute__((ext_vector_type(8)));
typedef unsigned short u16x8 __attribute__((ext_vector_type(8)));
typedef float f32x4 __attribute__((ext_vector_type(4)));

__device__ inline bf16x8 ld_frag_lds(const unsigned char* p) {
    union { u16x8 u; bf16x8 b; } c;
    c.u = *(const u16x8*)p;
    return c.b;
}

__device__ inline uint2 f4_to_bf4(float4 f) {
    union { __hip_bfloat162 b; unsigned u; } lo, hi;
    lo.b = __float22bfloat162_rn(make_float2(f.x, f.y));
    hi.b = __float22bfloat162_rn(make_float2(f.z, f.w));
    return make_uint2(lo.u, hi.u);
}

__device__ inline float tanh_fast(float x) {
    float ax = fabsf(x);
    float e = __expf(-2.0f * ax);
    float t = (1.0f - e) * __builtin_amdgcn_rcpf(1.0f + e);
    return x < 0.0f ? -t : t;
}

// ---------------------------------------------------------------------------
// Kernel 1: h_proj (fp32), We -> bf16 PRE-SWIZZLED LDS image, v copy, sums=0.
// Swizzle: byte offset for (d, ebyte) is d*256 + (ebyte ^ ((d&7)<<4)).
// This makes the logits kernel's staging an identity global->LDS DMA while
// keeping ds_read_b128 bank-even (8 accesses/bank).
// grid 64 x 256
// ---------------------------------------------------------------------------
__global__ __launch_bounds__(256) void prep_kernel(
        const float* __restrict__ hidden, const float* __restrict__ W_attn,
        const float* __restrict__ b_attn, const float* __restrict__ v_w,
        float* __restrict__ hproj, unsigned char* __restrict__ Wb,
        float* __restrict__ v_out, float* __restrict__ sums) {
    const int b = blockIdx.x;
    const int t = threadIdx.x;
    if (t == 0) sums[b] = 0.0f;          // re-zeroed every iteration, pre-logits
    if (t < 128) {
        float acc = b_attn[t];
        const float4* hrow = (const float4*)(hidden + b * DD);
        const float4* wrow = (const float4*)(W_attn + t * FAN);
        #pragma unroll
        for (int e = 0; e < 32; e++) {
            float4 h = hrow[e], w = wrow[e];
            acc += h.x * w.x + h.y * w.y + h.z * w.z + h.w * w.w;
        }
        hproj[b * DD + t] = acc;
        if (b == 0) v_out[t] = v_w[t];
    } else {
        int tt = t - 128;
        int d  = 2 * b + (tt >> 6);
        int e0 = (tt & 63) * 2;          // even element index; writes pair (e0,e0+1)
        float2 src = *(const float2*)(W_attn + d * FAN + DD + e0);
        union { __hip_bfloat162 bb; unsigned u; } c;
        c.bb = __float22bfloat162_rn(src);
        unsigned off = (unsigned)(d * 256)
                     + (((unsigned)(e0 * 2)) ^ (((unsigned)d & 7u) << 4));
        *(unsigned*)(Wb + off) = c.u;
    }
}

// ---------------------------------------------------------------------------
// Kernel 2: out[b][s] = exp(v . tanh(hproj[b] + X[s] @ We^T)) (0 if masked),
// atomicAdd per-row partial sums. No max-pass needed: |logit| <= ||v||_1
// <= 128/sqrt(128) = 11.31, exp <= 8.2e4 — no overflow possible.
// t-outer loop: each B-frag (Ws) is read from LDS ONCE per block and reused
// across both s-tiles (halves LDS traffic vs tile-outer).
// grid (32, 64) x 256.
// ---------------------------------------------------------------------------
__global__ __launch_bounds__(256, 4) void logits_kernel(
        const float* __restrict__ seq_embs, const int* __restrict__ mask,
        const float* __restrict__ hproj, const unsigned char* __restrict__ Wb,
        const float* __restrict__ v, float* __restrict__ out,
        float* __restrict__ sums) {
    __shared__ __attribute__((aligned(1024))) unsigned char Ws[DD * EE * 2]; // 32 KB

    const int b    = blockIdx.y;
    const int g    = blockIdx.x;
    const int tid  = threadIdx.x;
    const int wave = tid >> 6;
    const int lane = tid & 63;
    const int m    = lane & 15;
    const int quad = lane >> 4;

    // --- Stage swizzled We image via direct global->LDS DMA (identity copy).
    // Dest = wave-uniform base + lane*16 (HW rule); source mirrors it.
    #pragma unroll
    for (int j = 0; j < 8; j++) {
        const int c = wave * 8 + j;
        __builtin_amdgcn_global_load_lds(
            (const __attribute__((address_space(1))) unsigned int*)(Wb + c * 1024 + lane * 16),
            (__attribute__((address_space(3))) unsigned int*)(Ws + c * 1024),
            16, 0, 0);
    }

    // --- Load masks + A-fragments for both tiles (mask-skip halves HBM fetch).
    const int* __restrict__ mask_g = mask + (size_t)b * SS + g * ROWS;
    int  am[TILES];
    int4 mq[TILES];
    bf16x8 af[TILES][4];
    const float* __restrict__ xb = seq_embs
        + (size_t)(g * ROWS + wave * 16 + m) * (BB * EE)
        + (size_t)b * EE + quad * 8;
    #pragma unroll
    for (int tl = 0; tl < TILES; tl++) {
        am[tl] = mask_g[tl * 64 + wave * 16 + m];
        mq[tl] = *(const int4*)(mask_g + tl * 64 + wave * 16 + quad * 4);
        const float* xr = xb + (size_t)(tl * 64) * (BB * EE);
        #pragma unroll
        for (int kk = 0; kk < 4; kk++) {
            union { uint4 q; bf16x8 bf; } cc;
            cc.q = make_uint4(0u, 0u, 0u, 0u);
            if (am[tl] != 0) {
                float4 f0 = *(const float4*)(xr + kk * 32);
                float4 f1 = *(const float4*)(xr + kk * 32 + 4);
                uint2 a = f4_to_bf4(f0), bq = f4_to_bf4(f1);
                cc.q = make_uint4(a.x, a.y, bq.x, bq.y);
            }
            af[tl][kk] = cc.bf;
        }
    }

    // --- Per-lane epilogue constants (L2-hot).
    float hp_r[8], v_r[8];
    #pragma unroll
    for (int t = 0; t < 8; t++) {
        hp_r[t] = hproj[b * DD + t * 16 + m];
        v_r[t]  = v[t * 16 + m];
    }

    __syncthreads();   // compiler drains vmcnt(0): staging + A-loads complete

    float part[TILES][4];
    #pragma unroll
    for (int tl = 0; tl < TILES; tl++)
        #pragma unroll
        for (int r = 0; r < 4; r++) part[tl][r] = 0.0f;

    const unsigned sw = ((unsigned)(m & 7)) << 4;   // read-side XOR (matches prep)
    #pragma unroll
    for (int t = 0; t < 8; t++) {
        const unsigned rbase = (unsigned)((t * 16 + m) * 256);
        bf16x8 bf[4];
        #pragma unroll
        for (int kk = 0; kk < 4; kk++) {
            const unsigned cb = ((unsigned)(kk * 64 + quad * 16)) ^ sw;
            bf[kk] = ld_frag_lds(Ws + rbase + cb);
        }
        #pragma unroll
        for (int tl = 0; tl < TILES; tl++) {
            f32x4 acc = (f32x4){0.f, 0.f, 0.f, 0.f};
            #pragma unroll
            for (int kk = 0; kk < 4; kk++)
                acc = __builtin_amdgcn_mfma_f32_16x16x32_bf16(af[tl][kk], bf[kk], acc, 0, 0, 0);
            // Incremental epilogue: partial logit over this 16-wide d-slab.
            #pragma unroll
            for (int r = 0; r < 4; r++)
                part[tl][r] += v_r[t] * tanh_fast(hp_r[t] + acc[r]);
        }
    }

    // --- Reduce across the 16 m-lanes (d-dimension), exp, store, row sums.
    // Masked A-rows were zero-filled, so part[] is finite everywhere: the
    // unguarded butterfly is safe; masked outputs become exactly 0.
    float blocksum = 0.0f;
    #pragma unroll
    for (int tl = 0; tl < TILES; tl++) {
        const int mqa[4] = {mq[tl].x, mq[tl].y, mq[tl].z, mq[tl].w};
        float red[4];
        #pragma unroll
        for (int r = 0; r < 4; r++) {
            float p = part[tl][r];
            p += __shfl_xor(p, 1);
            p += __shfl_xor(p, 2);
            p += __shfl_xor(p, 4);
            p += __shfl_xor(p, 8);
            red[r] = (mqa[r] != 0) ? __expf(p) : 0.0f;
            blocksum += red[r];
        }
        if (m == 0) {
            *(float4*)&out[(size_t)b * SS + g * ROWS + tl * 64 + wave * 16 + quad * 4] =
                make_float4(red[0], red[1], red[2], red[3]);
        }
    }
    // blocksum is duplicated across the 16 m-lanes; sum the 4 quad groups.
    blocksum += __shfl_xor(blocksum, 16);
    blocksum += __shfl_xor(blocksum, 32);
    if (lane == 0) atomicAdd(&sums[b], blocksum);
}

// ---------------------------------------------------------------------------
// Kernel 3: out[b][s] /= sums[b]. Streaming, full-width grid (4, 64) x 256.
// ---------------------------------------------------------------------------
__global__ __launch_bounds__(256) void norm_kernel(
        float* __restrict__ out, const float* __restrict__ sums) {
    const int b = blockIdx.y;
    const float inv = 1.0f / sums[b];
    const int i = (blockIdx.x * 256 + threadIdx.x) * 4;
    float4 v = *(float4*)&out[(size_t)b * SS + i];
    v.x *= inv; v.y *= inv; v.z *= inv; v.w *= inv;
    *(float4*)&out[(size_t)b * SS + i] = v;
}

extern "C" void kernel_launch(void* const* d_in, const int* in_sizes, int n_in,
                              void* d_out, int out_size, void* d_ws, size_t ws_size,
                              hipStream_t stream) {
    const float* hidden   = (const float*)d_in[0];
    const float* seq_embs = (const float*)d_in[1];
    const int*   mask     = (const int*)d_in[2];
    const float* W_attn   = (const float*)d_in[3];
    const float* b_attn   = (const float*)d_in[4];
    const float* v_w      = (const float*)d_in[5];
    float* out = (float*)d_out;

    float*         hproj = (float*)d_ws;                            // 32 KB
    unsigned char* Wb    = (unsigned char*)d_ws + 32768;            // 32 KB swizzled image
    float*         vv    = (float*)((char*)d_ws + 65536);           // 512 B
    float*         sums  = (float*)((char*)d_ws + 66048);           // 256 B

    prep_kernel<<<64, 256, 0, stream>>>(hidden, W_attn, b_attn, v_w, hproj, Wb, vv, sums);
    dim3 grid(SS / ROWS, BB);          // (32, 64)
    logits_kernel<<<grid, 256, 0, stream>>>(seq_embs, mask, hproj, Wb, vv, out, sums);
    dim3 ngrid(SS / (256 * 4), BB);    // (4, 64)
    norm_kernel<<<ngrid, 256, 0, stream>>>(out, sums);
}

// Round 3
// 228.517 us; speedup vs baseline: 1.1446x; 1.1446x over previous
//
#include <hip/hip_runtime.h>
#include <hip/hip_bf16.h>

#define BB 64
#define SS 4096
#define EE 128   // EMB_DIM
#define DD 128   // DEC_DIM
#define FAN 256
#define TILES 4            // 64-row s-tiles per logits block
#define ROWS (TILES * 64)  // 256 s-rows per block
#define NEG_INF_F (-1e10f)

typedef __bf16 bf16x8 __attribute__((ext_vector_type(8)));
typedef unsigned short u16x8 __attribute__((ext_vector_type(8)));
typedef float f32x4 __attribute__((ext_vector_type(4)));

__device__ inline bf16x8 ld_frag_lds(const unsigned char* p) {
    union { u16x8 u; bf16x8 b; } c;
    c.u = *(const u16x8*)p;
    return c.b;
}

__device__ inline uint2 f4_to_bf4(float4 f) {
    union { __hip_bfloat162 b; unsigned u; } lo, hi;
    lo.b = __float22bfloat162_rn(make_float2(f.x, f.y));
    hi.b = __float22bfloat162_rn(make_float2(f.z, f.w));
    return make_uint2(lo.u, hi.u);
}

__device__ inline float tanh_fast(float x) {
    float ax = fabsf(x);
    float e = __expf(-2.0f * ax);
    float t = (1.0f - e) * __builtin_amdgcn_rcpf(1.0f + e);
    return x < 0.0f ? -t : t;
}

// ---------------------------------------------------------------------------
// Kernel 1: h_proj (fp32), We -> bf16 PRE-SWIZZLED LDS image, v copy, sums=0.
// Swizzle: byte offset for (d, ebyte) is d*256 + (ebyte ^ ((d&7)<<4)).
// Staging in the logits kernel is then an identity global->LDS DMA while
// ds_read_b128 stays bank-even (verified correct in the R2 run).
// grid 64 x 256
// ---------------------------------------------------------------------------
__global__ __launch_bounds__(256) void prep_kernel(
        const float* __restrict__ hidden, const float* __restrict__ W_attn,
        const float* __restrict__ b_attn, const float* __restrict__ v_w,
        float* __restrict__ hproj, unsigned char* __restrict__ Wb,
        float* __restrict__ v_out, float* __restrict__ sums) {
    const int b = blockIdx.x;
    const int t = threadIdx.x;
    if (t == 0) sums[b] = 0.0f;          // re-zeroed every replay, pre-logits
    if (t < 128) {
        float acc = b_attn[t];
        const float4* hrow = (const float4*)(hidden + b * DD);
        const float4* wrow = (const float4*)(W_attn + t * FAN);
        #pragma unroll
        for (int e = 0; e < 32; e++) {
            float4 h = hrow[e], w = wrow[e];
            acc += h.x * w.x + h.y * w.y + h.z * w.z + h.w * w.w;
        }
        hproj[b * DD + t] = acc;
        if (b == 0) v_out[t] = v_w[t];
    } else {
        int tt = t - 128;
        int d  = 2 * b + (tt >> 6);
        int e0 = (tt & 63) * 2;          // even element index; writes pair (e0,e0+1)
        float2 src = *(const float2*)(W_attn + d * FAN + DD + e0);
        union { __hip_bfloat162 bb; unsigned u; } c;
        c.bb = __float22bfloat162_rn(src);
        unsigned off = (unsigned)(d * 256)
                     + (((unsigned)(e0 * 2)) ^ (((unsigned)d & 7u) << 4));
        *(unsigned*)(Wb + off) = c.u;
    }
}

// ---------------------------------------------------------------------------
// Kernel 2 (R0 structure + R2-verified staging/exp-fusion):
// out[b][s] = exp(v . tanh(hproj[b] + X[s] @ We^T)) (0 if masked);
// atomicAdd per-row partial sums. Max-free exp is safe: |logit| <= ||v||_1
// <= 128/sqrt(128) = 11.31.
// - kk-outer / t-inner MFMA: 8 INDEPENDENT acc chains (ILP), epilogue
//   deferred until after the full MFMA loop.      [R2 regression cause #1]
// - mask-guarded tanh epilogue: skip ~50% rows.   [R2 regression cause #2]
// - double-buffered next-tile A-prefetch overlapping MFMA+epilogue.
// grid (16, 64) x 256.
// ---------------------------------------------------------------------------
__global__ __launch_bounds__(256, 4) void logits_kernel(
        const float* __restrict__ seq_embs, const int* __restrict__ mask,
        const float* __restrict__ hproj, const unsigned char* __restrict__ Wb,
        const float* __restrict__ v, float* __restrict__ out,
        float* __restrict__ sums) {
    __shared__ __attribute__((aligned(1024))) unsigned char Ws[DD * EE * 2]; // 32 KB

    const int b    = blockIdx.y;
    const int g    = blockIdx.x;
    const int tid  = threadIdx.x;
    const int wave = tid >> 6;
    const int lane = tid & 63;
    const int m    = lane & 15;
    const int quad = lane >> 4;
    const int arow = wave * 16 + m;       // this lane's s-row within each tile

    // --- Stage swizzled We image via direct global->LDS DMA (identity copy).
    // Dest = wave-uniform base + lane*16 (HW rule); source mirrors it.
    #pragma unroll
    for (int j = 0; j < 8; j++) {
        const int c = wave * 8 + j;
        __builtin_amdgcn_global_load_lds(
            (const __attribute__((address_space(1))) unsigned int*)(Wb + c * 1024 + lane * 16),
            (__attribute__((address_space(3))) unsigned int*)(Ws + c * 1024),
            16, 0, 0);
    }

    const int* __restrict__ mask_g = mask + (size_t)b * SS + g * ROWS;
    const float* __restrict__ xbase = seq_embs
        + (size_t)(g * ROWS + arow) * (BB * EE)
        + (size_t)b * EE + quad * 8;

    // --- Prefetch tile 0's mask + A-frags while the staging DMA is in flight.
    int am[2];
    int4 mq[2];
    bf16x8 af[2][4];
    {
        am[0] = mask_g[arow];
        mq[0] = *(const int4*)(mask_g + wave * 16 + quad * 4);
        const float* xrow = xbase;
        #pragma unroll
        for (int kk = 0; kk < 4; kk++) {
            union { uint4 q; bf16x8 bf; } c;
            c.q = make_uint4(0u, 0u, 0u, 0u);
            if (am[0] != 0) {
                float4 f0 = *(const float4*)(xrow + kk * 32);
                float4 f1 = *(const float4*)(xrow + kk * 32 + 4);
                uint2 a = f4_to_bf4(f0), bq = f4_to_bf4(f1);
                c.q = make_uint4(a.x, a.y, bq.x, bq.y);
            }
            af[0][kk] = c.bf;
        }
    }

    // --- Per-lane epilogue constants (L2-hot).
    float hp_r[8], v_r[8];
    #pragma unroll
    for (int t = 0; t < 8; t++) {
        hp_r[t] = hproj[b * DD + t * 16 + m];
        v_r[t]  = v[t * 16 + m];
    }

    __syncthreads();   // drains vmcnt(0): staging DMA + tile-0 A-loads complete

    const unsigned sw = ((unsigned)(m & 7)) << 4;   // read-side XOR (matches prep)
    float blocksum = 0.0f;

    #pragma unroll
    for (int tile = 0; tile < TILES; tile++) {
        const int cur = tile & 1;
        // Prefetch next tile's mask + A-frags (independent of this tile's MFMA).
        if (tile + 1 < TILES) {
            const int nxt = cur ^ 1;
            am[nxt] = mask_g[(tile + 1) * 64 + arow];
            mq[nxt] = *(const int4*)(mask_g + (tile + 1) * 64 + wave * 16 + quad * 4);
            const float* xrow = xbase + (size_t)((tile + 1) * 64) * (BB * EE);
            #pragma unroll
            for (int kk = 0; kk < 4; kk++) {
                union { uint4 q; bf16x8 bf; } c;
                c.q = make_uint4(0u, 0u, 0u, 0u);
                if (am[nxt] != 0) {
                    float4 f0 = *(const float4*)(xrow + kk * 32);
                    float4 f1 = *(const float4*)(xrow + kk * 32 + 4);
                    uint2 a = f4_to_bf4(f0), bq = f4_to_bf4(f1);
                    c.q = make_uint4(a.x, a.y, bq.x, bq.y);
                }
                af[nxt][kk] = c.bf;
            }
        }

        // --- MFMA: 64 s-rows x 128 d, K=128. 8 independent acc chains.
        f32x4 acc[8];
        #pragma unroll
        for (int t = 0; t < 8; t++) acc[t] = (f32x4){0.f, 0.f, 0.f, 0.f};
        #pragma unroll
        for (int kk = 0; kk < 4; kk++) {
            const unsigned cb = ((unsigned)(kk * 64 + quad * 16)) ^ sw;
            #pragma unroll
            for (int t = 0; t < 8; t++) {
                bf16x8 bf = ld_frag_lds(Ws + (unsigned)((t * 16 + m) * 256) + cb);
                acc[t] = __builtin_amdgcn_mfma_f32_16x16x32_bf16(af[cur][kk], bf, acc[t], 0, 0, 0);
            }
        }

        // --- Deferred epilogue: logit -> exp, mask-guarded (skip ~50% rows).
        const int mqa[4] = {mq[cur].x, mq[cur].y, mq[cur].z, mq[cur].w};
        float red[4];
        #pragma unroll
        for (int r = 0; r < 4; r++) {
            float red_r = 0.0f;
            if (mqa[r] != 0) {   // uniform across the 16-lane m-group: shfl-safe
                float part = 0.f;
                #pragma unroll
                for (int t = 0; t < 8; t++)
                    part += v_r[t] * tanh_fast(hp_r[t] + acc[t][r]);
                part += __shfl_xor(part, 1);
                part += __shfl_xor(part, 2);
                part += __shfl_xor(part, 4);
                part += __shfl_xor(part, 8);
                red_r = __expf(part);
            }
            red[r] = red_r;
            blocksum += red_r;
        }
        if (m == 0) {
            *(float4*)&out[(size_t)b * SS + g * ROWS + tile * 64
                           + wave * 16 + quad * 4] =
                make_float4(red[0], red[1], red[2], red[3]);
        }
    }

    // blocksum is duplicated across the 16 m-lanes; sum the 4 quad groups.
    blocksum += __shfl_xor(blocksum, 16);
    blocksum += __shfl_xor(blocksum, 32);
    if (lane == 0) atomicAdd(&sums[b], blocksum);
}

// ---------------------------------------------------------------------------
// Kernel 3: out[b][s] /= sums[b]. Streaming, full-width grid (4, 64) x 256.
// ---------------------------------------------------------------------------
__global__ __launch_bounds__(256) void norm_kernel(
        float* __restrict__ out, const float* __restrict__ sums) {
    const int b = blockIdx.y;
    const float inv = 1.0f / sums[b];
    const int i = (blockIdx.x * 256 + threadIdx.x) * 4;
    float4 v = *(float4*)&out[(size_t)b * SS + i];
    v.x *= inv; v.y *= inv; v.z *= inv; v.w *= inv;
    *(float4*)&out[(size_t)b * SS + i] = v;
}

extern "C" void kernel_launch(void* const* d_in, const int* in_sizes, int n_in,
                              void* d_out, int out_size, void* d_ws, size_t ws_size,
                              hipStream_t stream) {
    const float* hidden   = (const float*)d_in[0];
    const float* seq_embs = (const float*)d_in[1];
    const int*   mask     = (const int*)d_in[2];
    const float* W_attn   = (const float*)d_in[3];
    const float* b_attn   = (const float*)d_in[4];
    const float* v_w      = (const float*)d_in[5];
    float* out = (float*)d_out;

    float*         hproj = (float*)d_ws;                            // 32 KB
    unsigned char* Wb    = (unsigned char*)d_ws + 32768;            // 32 KB swizzled image
    float*         vv    = (float*)((char*)d_ws + 65536);           // 512 B
    float*         sums  = (float*)((char*)d_ws + 66048);           // 256 B

    prep_kernel<<<64, 256, 0, stream>>>(hidden, W_attn, b_attn, v_w, hproj, Wb, vv, sums);
    dim3 grid(SS / ROWS, BB);          // (16, 64)
    logits_kernel<<<grid, 256, 0, stream>>>(seq_embs, mask, hproj, Wb, vv, out, sums);
    dim3 ngrid(SS / (256 * 4), BB);    // (4, 64)
    norm_kernel<<<ngrid, 256, 0, stream>>>(out, sums);
}

// Round 4
// 211.433 us; speedup vs baseline: 1.2370x; 1.0808x over previous
//
#include <hip/hip_runtime.h>
#include <hip/hip_bf16.h>

#define BB 64
#define SS 4096
#define EE 128   // EMB_DIM
#define DD 128   // DEC_DIM
#define FAN 256
#define TILES 4            // 64-row s-tiles per logits block
#define ROWS (TILES * 64)  // 256 s-rows per block
#define NEG_INF_F (-1e10f)

typedef __bf16 bf16x8 __attribute__((ext_vector_type(8)));
typedef unsigned short u16x8 __attribute__((ext_vector_type(8)));
typedef float f32x4 __attribute__((ext_vector_type(4)));

__device__ inline bf16x8 ld_frag_lds(const unsigned char* p) {
    union { u16x8 u; bf16x8 b; } c;
    c.u = *(const u16x8*)p;
    return c.b;
}

__device__ inline uint2 f4_to_bf4(float4 f) {
    union { __hip_bfloat162 b; unsigned u; } lo, hi;
    lo.b = __float22bfloat162_rn(make_float2(f.x, f.y));
    hi.b = __float22bfloat162_rn(make_float2(f.z, f.w));
    return make_uint2(lo.u, hi.u);
}

__device__ inline float tanh_fast(float x) {
    float ax = fabsf(x);
    float e = __expf(-2.0f * ax);
    float t = (1.0f - e) * __builtin_amdgcn_rcpf(1.0f + e);
    return x < 0.0f ? -t : t;
}

// ---------------------------------------------------------------------------
// Kernel 1: h_proj (fp32), We -> bf16 PRE-SWIZZLED LDS image, v copy.
// Swizzle: byte offset for (d, ebyte) is d*256 + (ebyte ^ ((d&7)<<4)).
// grid 64 x 256
// ---------------------------------------------------------------------------
__global__ __launch_bounds__(256) void prep_kernel(
        const float* __restrict__ hidden, const float* __restrict__ W_attn,
        const float* __restrict__ b_attn, const float* __restrict__ v_w,
        float* __restrict__ hproj, unsigned char* __restrict__ Wb,
        float* __restrict__ v_out) {
    const int b = blockIdx.x;
    const int t = threadIdx.x;
    if (t < 128) {
        float acc = b_attn[t];
        const float4* hrow = (const float4*)(hidden + b * DD);
        const float4* wrow = (const float4*)(W_attn + t * FAN);
        #pragma unroll
        for (int e = 0; e < 32; e++) {
            float4 h = hrow[e], w = wrow[e];
            acc += h.x * w.x + h.y * w.y + h.z * w.z + h.w * w.w;
        }
        hproj[b * DD + t] = acc;
        if (b == 0) v_out[t] = v_w[t];
    } else {
        int tt = t - 128;
        int d  = 2 * b + (tt >> 6);
        int e0 = (tt & 63) * 2;          // even element index; writes pair (e0,e0+1)
        float2 src = *(const float2*)(W_attn + d * FAN + DD + e0);
        union { __hip_bfloat162 bb; unsigned u; } c;
        c.bb = __float22bfloat162_rn(src);
        unsigned off = (unsigned)(d * 256)
                     + (((unsigned)(e0 * 2)) ^ (((unsigned)d & 7u) << 4));
        *(unsigned*)(Wb + off) = c.u;
    }
}

// ---------------------------------------------------------------------------
// Kernel 2: out[b][s] = exp(v . tanh(hproj[b] + X[s] @ We^T)) (0 if masked).
// Max-free exp is safe: |logit| <= ||v||_1 <= 128/sqrt(128) = 11.31.
// Row-sum partials go to psums[b][g][wave] via PLAIN STORES — the R3
// atomicAdd to 2 hot cache lines from 1024 blocks across 8 XCDs is the
// suspected +17us regression (cross-XCD line migration, ~2048 serialized
// bounces per line). One store per wave, zero contention.
// grid (16, 64) x 256.
// ---------------------------------------------------------------------------
__global__ __launch_bounds__(256, 4) void logits_kernel(
        const float* __restrict__ seq_embs, const int* __restrict__ mask,
        const float* __restrict__ hproj, const unsigned char* __restrict__ Wb,
        const float* __restrict__ v, float* __restrict__ out,
        float* __restrict__ psums) {
    __shared__ __attribute__((aligned(1024))) unsigned char Ws[DD * EE * 2]; // 32 KB

    const int b    = blockIdx.y;
    const int g    = blockIdx.x;
    const int tid  = threadIdx.x;
    const int wave = tid >> 6;
    const int lane = tid & 63;
    const int m    = lane & 15;
    const int quad = lane >> 4;
    const int arow = wave * 16 + m;       // this lane's s-row within each tile

    // --- Stage swizzled We image via direct global->LDS DMA (identity copy).
    #pragma unroll
    for (int j = 0; j < 8; j++) {
        const int c = wave * 8 + j;
        __builtin_amdgcn_global_load_lds(
            (const __attribute__((address_space(1))) unsigned int*)(Wb + c * 1024 + lane * 16),
            (__attribute__((address_space(3))) unsigned int*)(Ws + c * 1024),
            16, 0, 0);
    }

    const int* __restrict__ mask_g = mask + (size_t)b * SS + g * ROWS;
    const float* __restrict__ xbase = seq_embs
        + (size_t)(g * ROWS + arow) * (BB * EE)
        + (size_t)b * EE + quad * 8;

    // --- Prefetch tile 0's mask + A-frags while the staging DMA is in flight.
    int am[2];
    int4 mq[2];
    bf16x8 af[2][4];
    {
        am[0] = mask_g[arow];
        mq[0] = *(const int4*)(mask_g + wave * 16 + quad * 4);
        const float* xrow = xbase;
        #pragma unroll
        for (int kk = 0; kk < 4; kk++) {
            union { uint4 q; bf16x8 bf; } c;
            c.q = make_uint4(0u, 0u, 0u, 0u);
            if (am[0] != 0) {
                float4 f0 = *(const float4*)(xrow + kk * 32);
                float4 f1 = *(const float4*)(xrow + kk * 32 + 4);
                uint2 a = f4_to_bf4(f0), bq = f4_to_bf4(f1);
                c.q = make_uint4(a.x, a.y, bq.x, bq.y);
            }
            af[0][kk] = c.bf;
        }
    }

    // --- Per-lane epilogue constants (L2-hot).
    float hp_r[8], v_r[8];
    #pragma unroll
    for (int t = 0; t < 8; t++) {
        hp_r[t] = hproj[b * DD + t * 16 + m];
        v_r[t]  = v[t * 16 + m];
    }

    __syncthreads();   // drains vmcnt(0): staging DMA + tile-0 A-loads complete

    const unsigned sw = ((unsigned)(m & 7)) << 4;   // read-side XOR (matches prep)
    float blocksum = 0.0f;

    #pragma unroll
    for (int tile = 0; tile < TILES; tile++) {
        const int cur = tile & 1;
        // Prefetch next tile's mask + A-frags (independent of this tile's MFMA).
        if (tile + 1 < TILES) {
            const int nxt = cur ^ 1;
            am[nxt] = mask_g[(tile + 1) * 64 + arow];
            mq[nxt] = *(const int4*)(mask_g + (tile + 1) * 64 + wave * 16 + quad * 4);
            const float* xrow = xbase + (size_t)((tile + 1) * 64) * (BB * EE);
            #pragma unroll
            for (int kk = 0; kk < 4; kk++) {
                union { uint4 q; bf16x8 bf; } c;
                c.q = make_uint4(0u, 0u, 0u, 0u);
                if (am[nxt] != 0) {
                    float4 f0 = *(const float4*)(xrow + kk * 32);
                    float4 f1 = *(const float4*)(xrow + kk * 32 + 4);
                    uint2 a = f4_to_bf4(f0), bq = f4_to_bf4(f1);
                    c.q = make_uint4(a.x, a.y, bq.x, bq.y);
                }
                af[nxt][kk] = c.bf;
            }
        }

        // --- MFMA: 64 s-rows x 128 d, K=128. 8 independent acc chains.
        f32x4 acc[8];
        #pragma unroll
        for (int t = 0; t < 8; t++) acc[t] = (f32x4){0.f, 0.f, 0.f, 0.f};
        #pragma unroll
        for (int kk = 0; kk < 4; kk++) {
            const unsigned cb = ((unsigned)(kk * 64 + quad * 16)) ^ sw;
            #pragma unroll
            for (int t = 0; t < 8; t++) {
                bf16x8 bf = ld_frag_lds(Ws + (unsigned)((t * 16 + m) * 256) + cb);
                acc[t] = __builtin_amdgcn_mfma_f32_16x16x32_bf16(af[cur][kk], bf, acc[t], 0, 0, 0);
            }
        }

        // --- Deferred epilogue: logit -> exp, mask-guarded (skip ~50% rows).
        const int mqa[4] = {mq[cur].x, mq[cur].y, mq[cur].z, mq[cur].w};
        float red[4];
        #pragma unroll
        for (int r = 0; r < 4; r++) {
            float red_r = 0.0f;
            if (mqa[r] != 0) {   // uniform across the 16-lane m-group: shfl-safe
                float part = 0.f;
                #pragma unroll
                for (int t = 0; t < 8; t++)
                    part += v_r[t] * tanh_fast(hp_r[t] + acc[t][r]);
                part += __shfl_xor(part, 1);
                part += __shfl_xor(part, 2);
                part += __shfl_xor(part, 4);
                part += __shfl_xor(part, 8);
                red_r = __expf(part);
            }
            red[r] = red_r;
            blocksum += red_r;
        }
        if (m == 0) {
            *(float4*)&out[(size_t)b * SS + g * ROWS + tile * 64
                           + wave * 16 + quad * 4] =
                make_float4(red[0], red[1], red[2], red[3]);
        }
    }

    // blocksum is duplicated across the 16 m-lanes; sum the 4 quad groups,
    // then ONE plain store per wave (no atomics, no hot-line contention).
    blocksum += __shfl_xor(blocksum, 16);
    blocksum += __shfl_xor(blocksum, 32);
    if (lane == 0) psums[(b * 16 + g) * 4 + wave] = blocksum;
}

// ---------------------------------------------------------------------------
// Kernel 3: reduce the 64 per-wave partials of row b, then out[b][s] *= inv.
// grid (4, 64) x 256.
// ---------------------------------------------------------------------------
__global__ __launch_bounds__(256) void norm_kernel(
        float* __restrict__ out, const float* __restrict__ psums) {
    const int b = blockIdx.y;
    const int tid = threadIdx.x;
    const int lane = tid & 63;
    float p = psums[b * 64 + lane];          // 64 partials, L2-hot
    #pragma unroll
    for (int off = 32; off >= 1; off >>= 1)
        p += __shfl_xor(p, off);
    const float inv = 1.0f / p;              // all lanes hold the full sum
    const int i = (blockIdx.x * 256 + tid) * 4;
    float4 v = *(float4*)&out[(size_t)b * SS + i];
    v.x *= inv; v.y *= inv; v.z *= inv; v.w *= inv;
    *(float4*)&out[(size_t)b * SS + i] = v;
}

extern "C" void kernel_launch(void* const* d_in, const int* in_sizes, int n_in,
                              void* d_out, int out_size, void* d_ws, size_t ws_size,
                              hipStream_t stream) {
    const float* hidden   = (const float*)d_in[0];
    const float* seq_embs = (const float*)d_in[1];
    const int*   mask     = (const int*)d_in[2];
    const float* W_attn   = (const float*)d_in[3];
    const float* b_attn   = (const float*)d_in[4];
    const float* v_w      = (const float*)d_in[5];
    float* out = (float*)d_out;

    float*         hproj = (float*)d_ws;                            // 32 KB
    unsigned char* Wb    = (unsigned char*)d_ws + 32768;            // 32 KB swizzled image
    float*         vv    = (float*)((char*)d_ws + 65536);           // 512 B
    float*         psums = (float*)((char*)d_ws + 66048);           // 16 KB (64 x 64)

    prep_kernel<<<64, 256, 0, stream>>>(hidden, W_attn, b_attn, v_w, hproj, Wb, vv);
    dim3 grid(SS / ROWS, BB);          // (16, 64)
    logits_kernel<<<grid, 256, 0, stream>>>(seq_embs, mask, hproj, Wb, vv, out, psums);
    dim3 ngrid(SS / (256 * 4), BB);    // (4, 64)
    norm_kernel<<<ngrid, 256, 0, stream>>>(out, psums);
}